// Round 2
// baseline (1300.869 us; speedup 1.0000x reference)
//
#include <hip/hip_runtime.h>
#include <cstdint>
#include <cstddef>

typedef unsigned short u16;
typedef unsigned int u32;
typedef short s16x8 __attribute__((ext_vector_type(8)));   // 8 bf16 in 4 VGPRs
typedef float f32x4 __attribute__((ext_vector_type(4)));

// Problem constants: B=4,S=2048 -> T=8192 tokens, D=1024, H=4096, DO=1024, E=8, K=2
#define T_TOK 8192
#define D_IN  1024
#define H_DIM 4096
#define DO_DIM 1024
#define E_NUM 8

__device__ __forceinline__ u16 f2bf(float f) {  // RNE f32 -> bf16
    u32 u = __float_as_uint(f);
    return (u16)((u + 0x7FFFu + ((u >> 16) & 1u)) >> 16);
}

__device__ __forceinline__ f32x4 mfma16(s16x8 a, s16x8 b, f32x4 c) {
    return __builtin_amdgcn_mfma_f32_16x16x32_bf16(a, b, c, 0, 0, 0);
}

// XOR swizzle: tiles are [128 rows][64 bf16 = 128B]; spread 16B blocks across banks
__device__ __forceinline__ int swz(int row, int byteInRow) {
    return (row << 7) + (byteInRow ^ ((row & 7) << 4));
}

// ---------------- gate: logits (f32, deterministic tree-reduce), top-2, softmax,
// routing lists. One block per token. ----------------
__global__ __launch_bounds__(256) void gate_kernel(
    const float* __restrict__ x, const float* __restrict__ gw,
    const float* __restrict__ gb, float* __restrict__ weights_out,
    float* __restrict__ topi_out, int* __restrict__ counts,
    int* __restrict__ tok_list, int* __restrict__ slot_of_tok)
{
    const int t = blockIdx.x;
    const int tid = threadIdx.x;
    __shared__ float red[256][8];
    float p[8];
#pragma unroll
    for (int e = 0; e < 8; ++e) p[e] = 0.f;
    const float* xr = x + ((size_t)t << 10);
    for (int d = tid; d < D_IN; d += 256) {
        float xv = xr[d];
        const f32x4 g0 = *(const f32x4*)(gw + d * 8);
        const f32x4 g1 = *(const f32x4*)(gw + d * 8 + 4);
        p[0] += xv * g0[0]; p[1] += xv * g0[1]; p[2] += xv * g0[2]; p[3] += xv * g0[3];
        p[4] += xv * g1[0]; p[5] += xv * g1[1]; p[6] += xv * g1[2]; p[7] += xv * g1[3];
    }
#pragma unroll
    for (int e = 0; e < 8; ++e) red[tid][e] = p[e];
    __syncthreads();
    for (int s = 128; s > 0; s >>= 1) {
        if (tid < s) {
#pragma unroll
            for (int e = 0; e < 8; ++e) red[tid][e] += red[tid + s][e];
        }
        __syncthreads();
    }
    if (tid == 0) {
        float lg[8];
#pragma unroll
        for (int e = 0; e < 8; ++e) lg[e] = red[0][e] + gb[e];
        int i0 = 0;
        for (int e = 1; e < 8; ++e) if (lg[e] > lg[i0]) i0 = e;           // ties -> lowest idx (matches top_k)
        int i1 = (i0 == 0) ? 1 : 0;
        for (int e = 0; e < 8; ++e) if (e != i0 && lg[e] > lg[i1]) i1 = e;
        float ex = expf(lg[i1] - lg[i0]);          // <= 1
        float p0 = 1.f / (1.f + ex);
        float p1 = ex / (1.f + ex);
#pragma unroll
        for (int e = 0; e < 8; ++e)
            weights_out[t * 8 + e] = (e == i0) ? p0 : ((e == i1) ? p1 : 0.f);
        topi_out[t * 2 + 0] = (float)i0;
        topi_out[t * 2 + 1] = (float)i1;
        int pos0 = atomicAdd(&counts[i0], 1);
        tok_list[(i0 << 13) + pos0] = t;
        slot_of_tok[t * 2 + 0] = (i0 << 13) + pos0;
        int pos1 = atomicAdd(&counts[i1], 1);
        tok_list[(i1 << 13) + pos1] = t;
        slot_of_tok[t * 2 + 1] = (i1 << 13) + pos1;
    }
}

__global__ void zero_counts_kernel(int* c) { if (threadIdx.x < 8) c[threadIdx.x] = 0; }

// exclusive scan of 8 counts -> base[], and expert_usage output (as f32)
__global__ void scan_kernel(const int* __restrict__ counts, int* __restrict__ base,
                            float* __restrict__ usage_out) {
    if (threadIdx.x == 0) {
        int acc = 0;
        for (int e = 0; e < 8; ++e) {
            base[e] = acc;
            acc += counts[e];
            usage_out[e] = (float)counts[e];
        }
    }
}

__global__ void zero_kernel(float* p, int n) {
    int i = blockIdx.x * 256 + threadIdx.x;
    if (i < n) p[i] = 0.f;
}

// ---------------- transpose+cvt: w1[e][d][h-chunk] -> w1t[e][hh][d] bf16;
// w2[e][h-chunk][o] -> w2t[e][o][hh] bf16. 64x64 tiles via LDS. ----------------
__global__ __launch_bounds__(256) void transpose_kernel(
    const float* __restrict__ w1, const float* __restrict__ w2,
    u16* __restrict__ w1t, u16* __restrict__ w2t, int chunk, int HC)
{
    const int e = blockIdx.z;
    const int tid = threadIdx.x;
    const int tiles_h = HC >> 6;
    const int ntile1 = 16 * tiles_h;   // w1: (1024/64) x (HC/64)
    int b = blockIdx.x;
    const float* src; u16* dst;
    size_t sstride, dstride;
    int r0, c0;
    if (b < ntile1) {
        int tr = b / tiles_h, tc = b % tiles_h;                 // tr over d, tc over hh
        r0 = tr * 64; c0 = tc * 64;
        src = w1 + (size_t)e * D_IN * H_DIM + (size_t)chunk * HC;   // src(r,c)=src[r*4096+c]
        sstride = H_DIM;
        dst = w1t + (size_t)e * HC * D_IN;                          // dst(c,r)=dst[c*1024+r]
        dstride = D_IN;
    } else {
        int tb = b - ntile1;
        int tr = tb / 16, tc = tb % 16;                         // tr over hh, tc over o
        r0 = tr * 64; c0 = tc * 64;
        src = w2 + ((size_t)e * H_DIM + (size_t)chunk * HC) * DO_DIM; // src(r,c)=src[r*1024+c]
        sstride = DO_DIM;
        dst = w2t + (size_t)e * DO_DIM * HC;                        // dst(c,r)=dst[c*HC+r]
        dstride = HC;
    }
    __shared__ u16 tile[64][68];
#pragma unroll
    for (int i = 0; i < 4; ++i) {
        int flat = i * 1024 + tid * 4;
        int rr = flat >> 6, cc = flat & 63;
        float4 v = *(const float4*)(src + (size_t)(r0 + rr) * sstride + c0 + cc);
        ushort4 h4;
        h4.x = f2bf(v.x); h4.y = f2bf(v.y); h4.z = f2bf(v.z); h4.w = f2bf(v.w);
        *(ushort4*)&tile[rr][cc] = h4;
    }
    __syncthreads();
#pragma unroll
    for (int i = 0; i < 4; ++i) {
        int flat = i * 1024 + tid * 4;
        int rr = flat >> 6, cc = flat & 63;   // rr: dst row (src col), cc: dst col base (src rows)
        ushort4 o;
        o.x = tile[cc + 0][rr]; o.y = tile[cc + 1][rr];
        o.z = tile[cc + 2][rr]; o.w = tile[cc + 3][rr];
        *(ushort4*)(dst + (size_t)(c0 + rr) * dstride + r0 + cc) = o;
    }
}

// ---------------- GEMM1: h[slot][hh] = relu(x[tok] @ w1[e] + b1[e]) (bf16 out)
// 128x128 tile, BK=64, 4 waves (2x2), 16x16x32 bf16 MFMA ----------------
__global__ __launch_bounds__(256) void gemm1_kernel(
    const float* __restrict__ x, const u16* __restrict__ w1t,
    const float* __restrict__ b1, u16* __restrict__ hbuf,
    const int* __restrict__ counts, const int* __restrict__ base,
    const int* __restrict__ tok_list, int chunk, int HC)
{
    const int e = blockIdx.z;
    const int n_e = counts[e];
    const int row0 = blockIdx.y * 128;
    if (row0 >= n_e) return;
    const int sbase = base[e];           // compact slot base for this expert
    const int col0 = blockIdx.x * 128;
    const int tid = threadIdx.x;
    const int lane = tid & 63;
    const int wv = tid >> 6;
    const int wr = (wv >> 1) * 64, wc = (wv & 1) * 64;

    __shared__ u16 Al[8192];
    __shared__ u16 Bl[8192];
    __shared__ int toks[128];

    if (tid < 128) {
        int r = row0 + tid;
        toks[tid] = (r < n_e) ? tok_list[(e << 13) + r] : -1;
    }
    __syncthreads();

    f32x4 zero = {0.f, 0.f, 0.f, 0.f};
    f32x4 acc[4][4];
#pragma unroll
    for (int m = 0; m < 4; ++m)
#pragma unroll
        for (int n = 0; n < 4; ++n) acc[m][n] = zero;

    const size_t wrow = (size_t)e * HC + col0;

    for (int ks = 0; ks < D_IN / 64; ++ks) {
        const int k0 = ks * 64;
        // stage A: gathered x rows, f32 -> bf16
#pragma unroll
        for (int i = 0; i < 8; ++i) {
            int flat = i * 1024 + tid * 4;
            int rr = flat >> 6, cc = flat & 63;
            int tk = toks[rr];
            float4 v = make_float4(0.f, 0.f, 0.f, 0.f);
            if (tk >= 0) v = *(const float4*)(x + ((size_t)tk << 10) + k0 + cc);
            ushort4 h4;
            h4.x = f2bf(v.x); h4.y = f2bf(v.y); h4.z = f2bf(v.z); h4.w = f2bf(v.w);
            *(ushort4*)((char*)Al + swz(rr, cc * 2)) = h4;
        }
        // stage B: w1t rows (already bf16, contiguous in k)
#pragma unroll
        for (int i = 0; i < 4; ++i) {
            int flat = i * 2048 + tid * 8;
            int rr = flat >> 6, cc = flat & 63;
            uint4 v = *(const uint4*)(w1t + (wrow + rr) * D_IN + k0 + cc);
            *(uint4*)((char*)Bl + swz(rr, cc * 2)) = v;
        }
        __syncthreads();
#pragma unroll
        for (int kk = 0; kk < 2; ++kk) {
            const int kb = kk * 64 + ((lane >> 4) << 4);
            s16x8 af[4], bfr[4];
#pragma unroll
            for (int m = 0; m < 4; ++m) {
                int r = wr + m * 16 + (lane & 15);
                af[m] = *(const s16x8*)((const char*)Al + swz(r, kb));
            }
#pragma unroll
            for (int n = 0; n < 4; ++n) {
                int r = wc + n * 16 + (lane & 15);
                bfr[n] = *(const s16x8*)((const char*)Bl + swz(r, kb));
            }
#pragma unroll
            for (int m = 0; m < 4; ++m)
#pragma unroll
                for (int n = 0; n < 4; ++n)
                    acc[m][n] = mfma16(af[m], bfr[n], acc[m][n]);
        }
        __syncthreads();
    }

    const int rb = wr + ((lane >> 4) << 2);   // C/D: row=(lane>>4)*4+reg, col=lane&15
    const int cb = wc + (lane & 15);
#pragma unroll
    for (int n = 0; n < 4; ++n) {
        int c = cb + n * 16;
        float bias = b1[(e << 12) + chunk * HC + col0 + c];
#pragma unroll
        for (int m = 0; m < 4; ++m) {
#pragma unroll
            for (int j = 0; j < 4; ++j) {
                int r = row0 + rb + m * 16 + j;
                if (r < n_e) {
                    float v = acc[m][n][j] + bias;
                    v = v > 0.f ? v : 0.f;
                    hbuf[(size_t)(sbase + r) * HC + col0 + c] = f2bf(v);
                }
            }
        }
    }
}

// ---------------- GEMM2: eo[slot][o] (+)= h[slot] @ w2[e] (+ b2 on chunk 0);
// or (small-ws fallback) atomic out accumulate scaled by gate weight ----------------
__global__ __launch_bounds__(256) void gemm2_kernel(
    const u16* __restrict__ hbuf, const u16* __restrict__ w2t,
    const float* __restrict__ b2, float* __restrict__ eo,
    float* __restrict__ out, const float* __restrict__ weights,
    const int* __restrict__ counts, const int* __restrict__ base,
    const int* __restrict__ tok_list, int chunk, int HC, int mode)
{
    const int e = blockIdx.z;
    const int n_e = counts[e];
    const int row0 = blockIdx.y * 128;
    if (row0 >= n_e) return;
    const int sbase = base[e];
    const int col0 = blockIdx.x * 128;
    const int tid = threadIdx.x;
    const int lane = tid & 63;
    const int wv = tid >> 6;
    const int wr = (wv >> 1) * 64, wc = (wv & 1) * 64;

    __shared__ u16 Al[8192];
    __shared__ u16 Bl[8192];
    __shared__ int toks[128];
    if (tid < 128) {
        int r = row0 + tid;
        toks[tid] = (r < n_e) ? tok_list[(e << 13) + r] : -1;
    }
    __syncthreads();

    f32x4 zero = {0.f, 0.f, 0.f, 0.f};
    f32x4 acc[4][4];
#pragma unroll
    for (int m = 0; m < 4; ++m)
#pragma unroll
        for (int n = 0; n < 4; ++n) acc[m][n] = zero;

    const int KST = HC >> 6;
    for (int ks = 0; ks < KST; ++ks) {
        const int k0 = ks * 64;
#pragma unroll
        for (int i = 0; i < 4; ++i) {   // A: h rows, bf16
            int flat = i * 2048 + tid * 8;
            int rr = flat >> 6, cc = flat & 63;
            uint4 v = make_uint4(0, 0, 0, 0);
            if (row0 + rr < n_e)
                v = *(const uint4*)(hbuf + (size_t)(sbase + row0 + rr) * HC + k0 + cc);
            *(uint4*)((char*)Al + swz(rr, cc * 2)) = v;
        }
#pragma unroll
        for (int i = 0; i < 4; ++i) {   // B: w2t rows, bf16
            int flat = i * 2048 + tid * 8;
            int rr = flat >> 6, cc = flat & 63;
            uint4 v = *(const uint4*)(w2t + ((size_t)(e << 10) + col0 + rr) * HC + k0 + cc);
            *(uint4*)((char*)Bl + swz(rr, cc * 2)) = v;
        }
        __syncthreads();
#pragma unroll
        for (int kk = 0; kk < 2; ++kk) {
            const int kb = kk * 64 + ((lane >> 4) << 4);
            s16x8 af[4], bfr[4];
#pragma unroll
            for (int m = 0; m < 4; ++m) {
                int r = wr + m * 16 + (lane & 15);
                af[m] = *(const s16x8*)((const char*)Al + swz(r, kb));
            }
#pragma unroll
            for (int n = 0; n < 4; ++n) {
                int r = wc + n * 16 + (lane & 15);
                bfr[n] = *(const s16x8*)((const char*)Bl + swz(r, kb));
            }
#pragma unroll
            for (int m = 0; m < 4; ++m)
#pragma unroll
                for (int n = 0; n < 4; ++n)
                    acc[m][n] = mfma16(af[m], bfr[n], acc[m][n]);
        }
        __syncthreads();
    }

    const int rb = wr + ((lane >> 4) << 2);
    const int cb = wc + (lane & 15);
#pragma unroll
    for (int n = 0; n < 4; ++n) {
        int c = cb + n * 16;
        int colg = col0 + c;
        float bias = (chunk == 0) ? b2[(e << 10) + colg] : 0.f;
#pragma unroll
        for (int m = 0; m < 4; ++m) {
#pragma unroll
            for (int j = 0; j < 4; ++j) {
                int lr = rb + m * 16 + j;
                int r = row0 + lr;
                if (r < n_e) {
                    float v = acc[m][n][j] + bias;
                    if (mode) {
                        float* ptr = eo + ((size_t)(sbase + r) << 10) + colg;
                        if (chunk == 0) *ptr = v; else *ptr += v;
                    } else {
                        int tk = toks[lr];
                        float gwt = weights[tk * 8 + e];
                        atomicAdd(out + ((size_t)tk << 10) + colg, gwt * v);
                    }
                }
            }
        }
    }
}

// ---------------- combine: out[t] = w0*eo[s0] + w1*eo[s1] (deterministic) ----------------
__global__ __launch_bounds__(256) void combine_kernel(
    const float* __restrict__ eo, const float* __restrict__ weights,
    const int* __restrict__ slot_of_tok, const int* __restrict__ base,
    float* __restrict__ out)
{
    const int t = blockIdx.x;
    const int tid = threadIdx.x;
    int s0 = slot_of_tok[t * 2], s1 = slot_of_tok[t * 2 + 1];
    int e0 = s0 >> 13, e1 = s1 >> 13;
    int c0 = base[e0] + (s0 & 8191);
    int c1 = base[e1] + (s1 & 8191);
    float w0 = weights[t * 8 + e0];
    float w1 = weights[t * 8 + e1];
    int c = tid * 4;
    f32x4 a = *(const f32x4*)(eo + ((size_t)c0 << 10) + c);
    f32x4 b = *(const f32x4*)(eo + ((size_t)c1 << 10) + c);
    f32x4 r;
    r[0] = w0 * a[0] + w1 * b[0];
    r[1] = w0 * a[1] + w1 * b[1];
    r[2] = w0 * a[2] + w1 * b[2];
    r[3] = w0 * a[3] + w1 * b[3];
    *(f32x4*)(out + ((size_t)t << 10) + c) = r;
}

extern "C" void kernel_launch(void* const* d_in, const int* in_sizes, int n_in,
                              void* d_out, int out_size, void* d_ws, size_t ws_size,
                              hipStream_t stream)
{
    const float* x      = (const float*)d_in[0];
    const float* gate_w = (const float*)d_in[1];
    const float* gate_b = (const float*)d_in[2];
    const float* w1     = (const float*)d_in[3];
    const float* b1     = (const float*)d_in[4];
    const float* w2     = (const float*)d_in[5];
    const float* b2     = (const float*)d_in[6];

    float* out         = (float*)d_out;                      // [8192,1024]
    float* weights_out = out + (size_t)T_TOK * DO_DIM;       // [8192,8]
    float* usage_out   = weights_out + (size_t)T_TOK * 8;    // [8]
    float* topi_out    = usage_out + 8;                      // [8192,2]

    char* p = (char*)d_ws;
    int* counts = (int*)p;       p += 256;
    int* base   = (int*)p;       p += 256;
    int* tok_list = (int*)p;     p += (size_t)8 * 8192 * 4;
    int* slot_of_tok = (int*)p;  p += (size_t)8192 * 2 * 4;
    const size_t fixed = (size_t)(p - (char*)d_ws);

    // per-HC bytes: w1t 8*HC*1024*2 + w2t 8*1024*HC*2 + hbuf 16384*HC*2 = 65536*HC
    // eo (compact, 16384 slots x 1024 f32) = 64 MiB
    const size_t eo_bytes = (size_t)16384 * 1024 * 4;
    int HC, use_eo;
    if      (ws_size >= fixed + (size_t)65536 * 4096 + eo_bytes) { HC = 4096; use_eo = 1; }
    else if (ws_size >= fixed + (size_t)65536 * 2048 + eo_bytes) { HC = 2048; use_eo = 1; }
    else if (ws_size >= fixed + (size_t)65536 * 1024 + eo_bytes) { HC = 1024; use_eo = 1; }
    else if (ws_size >= fixed + (size_t)65536 * 512  + eo_bytes) { HC = 512;  use_eo = 1; }
    else if (ws_size >= fixed + (size_t)65536 * 512)             { HC = 512;  use_eo = 0; }
    else if (ws_size >= fixed + (size_t)65536 * 256)             { HC = 256;  use_eo = 0; }
    else                                                         { HC = 128;  use_eo = 0; }

    u16* w1t  = (u16*)p; p += (size_t)8 * HC * 1024 * 2;
    u16* w2t  = (u16*)p; p += (size_t)8 * 1024 * HC * 2;
    u16* hbuf = (u16*)p; p += (size_t)16384 * HC * 2;
    float* eo = (float*)p;

    zero_counts_kernel<<<1, 64, 0, stream>>>(counts);
    gate_kernel<<<T_TOK, 256, 0, stream>>>(x, gate_w, gate_b, weights_out, topi_out,
                                           counts, tok_list, slot_of_tok);
    scan_kernel<<<1, 64, 0, stream>>>(counts, base, usage_out);
    if (!use_eo)
        zero_kernel<<<(T_TOK * DO_DIM + 255) / 256, 256, 0, stream>>>(out, T_TOK * DO_DIM);

    const int NC = H_DIM / HC;
    for (int c = 0; c < NC; ++c) {
        int tiles_h = HC / 64;
        transpose_kernel<<<dim3(2 * 16 * tiles_h, 1, 8), 256, 0, stream>>>(w1, w2, w1t, w2t, c, HC);
        gemm1_kernel<<<dim3(HC / 128, 64, 8), 256, 0, stream>>>(x, w1t, b1, hbuf,
                                                                counts, base, tok_list, c, HC);
        gemm2_kernel<<<dim3(DO_DIM / 128, 64, 8), 256, 0, stream>>>(hbuf, w2t, b2, eo, out,
                                                                    weights_out, counts, base,
                                                                    tok_list, c, HC, use_eo);
    }
    if (use_eo)
        combine_kernel<<<T_TOK, 256, 0, stream>>>(eo, weights_out, slot_of_tok, base, out);
}

// Round 3
// 717.611 us; speedup vs baseline: 1.8128x; 1.8128x over previous
//
#include <hip/hip_runtime.h>
#include <cstdint>
#include <cstddef>

typedef unsigned short u16;
typedef unsigned int u32;
typedef short s16x8 __attribute__((ext_vector_type(8)));   // 8 bf16 in 4 VGPRs
typedef float f32x4 __attribute__((ext_vector_type(4)));

// Problem constants: B=4,S=2048 -> T=8192 tokens, D=1024, H=4096, DO=1024, E=8, K=2
#define T_TOK 8192
#define D_IN  1024
#define H_DIM 4096
#define DO_DIM 1024

__device__ __forceinline__ u16 f2bf(float f) {  // RNE f32 -> bf16
    u32 u = __float_as_uint(f);
    return (u16)((u + 0x7FFFu + ((u >> 16) & 1u)) >> 16);
}

__device__ __forceinline__ f32x4 mfma16(s16x8 a, s16x8 b, f32x4 c) {
    return __builtin_amdgcn_mfma_f32_16x16x32_bf16(a, b, c, 0, 0, 0);
}

// async 16B global->LDS (direct DMA, no VGPR round trip)
__device__ __forceinline__ void gload16(const void* g, void* l) {
    __builtin_amdgcn_global_load_lds(
        (const __attribute__((address_space(1))) void*)g,
        (__attribute__((address_space(3))) void*)l,
        16, 0, 0);
}

// ---------------- gate: logits (f32, deterministic tree-reduce), top-2, softmax,
// routing lists. One block per token. ----------------
__global__ __launch_bounds__(256) void gate_kernel(
    const float* __restrict__ x, const float* __restrict__ gw,
    const float* __restrict__ gb, float* __restrict__ weights_out,
    float* __restrict__ topi_out, int* __restrict__ counts,
    int* __restrict__ tok_list, int* __restrict__ slot_of_tok)
{
    const int t = blockIdx.x;
    const int tid = threadIdx.x;
    __shared__ float red[256][8];
    float p[8];
#pragma unroll
    for (int e = 0; e < 8; ++e) p[e] = 0.f;
    const float* xr = x + ((size_t)t << 10);
    for (int d = tid; d < D_IN; d += 256) {
        float xv = xr[d];
        const f32x4 g0 = *(const f32x4*)(gw + d * 8);
        const f32x4 g1 = *(const f32x4*)(gw + d * 8 + 4);
        p[0] += xv * g0[0]; p[1] += xv * g0[1]; p[2] += xv * g0[2]; p[3] += xv * g0[3];
        p[4] += xv * g1[0]; p[5] += xv * g1[1]; p[6] += xv * g1[2]; p[7] += xv * g1[3];
    }
#pragma unroll
    for (int e = 0; e < 8; ++e) red[tid][e] = p[e];
    __syncthreads();
    for (int s = 128; s > 0; s >>= 1) {
        if (tid < s) {
#pragma unroll
            for (int e = 0; e < 8; ++e) red[tid][e] += red[tid + s][e];
        }
        __syncthreads();
    }
    if (tid == 0) {
        float lg[8];
#pragma unroll
        for (int e = 0; e < 8; ++e) lg[e] = red[0][e] + gb[e];
        int i0 = 0;
        for (int e = 1; e < 8; ++e) if (lg[e] > lg[i0]) i0 = e;   // ties -> lowest idx (matches top_k)
        int i1 = (i0 == 0) ? 1 : 0;
        for (int e = 0; e < 8; ++e) if (e != i0 && lg[e] > lg[i1]) i1 = e;
        float ex = expf(lg[i1] - lg[i0]);          // <= 1
        float p0 = 1.f / (1.f + ex);
        float p1 = ex / (1.f + ex);
#pragma unroll
        for (int e = 0; e < 8; ++e)
            weights_out[t * 8 + e] = (e == i0) ? p0 : ((e == i1) ? p1 : 0.f);
        topi_out[t * 2 + 0] = (float)i0;
        topi_out[t * 2 + 1] = (float)i1;
        int pos0 = atomicAdd(&counts[i0], 1);
        tok_list[(i0 << 13) + pos0] = t;
        slot_of_tok[t * 2 + 0] = (i0 << 13) + pos0;
        int pos1 = atomicAdd(&counts[i1], 1);
        tok_list[(i1 << 13) + pos1] = t;
        slot_of_tok[t * 2 + 1] = (i1 << 13) + pos1;
    }
}

__global__ void zero_counts_kernel(int* c) { if (threadIdx.x < 8) c[threadIdx.x] = 0; }

// exclusive scan of 8 counts -> base[], and expert_usage output (as f32)
__global__ void scan_kernel(const int* __restrict__ counts, int* __restrict__ base,
                            float* __restrict__ usage_out) {
    if (threadIdx.x == 0) {
        int acc = 0;
        for (int e = 0; e < 8; ++e) {
            base[e] = acc;
            acc += counts[e];
            usage_out[e] = (float)counts[e];
        }
    }
}

// ---------------- gather: xg[slot][d] = bf16(x[tok][d]) — compact slot-major A ----------------
__global__ __launch_bounds__(256) void gather_kernel(
    const float* __restrict__ x, const int* __restrict__ counts,
    const int* __restrict__ base, const int* __restrict__ tok_list,
    u16* __restrict__ xg)
{
    const int e = blockIdx.y;
    const int pos = blockIdx.x;
    if (pos >= counts[e]) return;
    const int slot = base[e] + pos;
    const int tok = tok_list[(e << 13) + pos];
    const int d = threadIdx.x * 4;
    float4 v = *(const float4*)(x + ((size_t)tok << 10) + d);
    ushort4 h;
    h.x = f2bf(v.x); h.y = f2bf(v.y); h.z = f2bf(v.z); h.w = f2bf(v.w);
    *(ushort4*)(xg + ((size_t)slot << 10) + d) = h;
}

// ---------------- transpose+cvt: w1[e][d][h-chunk] -> w1t[e][hh][d] bf16;
// w2[e][h-chunk][o] -> w2t[e][o][hh] bf16. 64x64 tiles via LDS. ----------------
__global__ __launch_bounds__(256) void transpose_kernel(
    const float* __restrict__ w1, const float* __restrict__ w2,
    u16* __restrict__ w1t, u16* __restrict__ w2t, int chunk, int HC)
{
    const int e = blockIdx.z;
    const int tid = threadIdx.x;
    const int tiles_h = HC >> 6;
    const int ntile1 = 16 * tiles_h;   // w1: (1024/64) x (HC/64)
    int b = blockIdx.x;
    const float* src; u16* dst;
    size_t sstride, dstride;
    int r0, c0;
    if (b < ntile1) {
        int tr = b / tiles_h, tc = b % tiles_h;                 // tr over d, tc over hh
        r0 = tr * 64; c0 = tc * 64;
        src = w1 + (size_t)e * D_IN * H_DIM + (size_t)chunk * HC;   // src(r,c)=src[r*4096+c]
        sstride = H_DIM;
        dst = w1t + (size_t)e * HC * D_IN;                          // dst(c,r)=dst[c*1024+r]
        dstride = D_IN;
    } else {
        int tb = b - ntile1;
        int tr = tb / 16, tc = tb % 16;                         // tr over hh, tc over o
        r0 = tr * 64; c0 = tc * 64;
        src = w2 + ((size_t)e * H_DIM + (size_t)chunk * HC) * DO_DIM; // src(r,c)=src[r*1024+c]
        sstride = DO_DIM;
        dst = w2t + (size_t)e * DO_DIM * HC;                        // dst(c,r)=dst[c*HC+r]
        dstride = HC;
    }
    __shared__ u16 tile[64][68];
#pragma unroll
    for (int i = 0; i < 4; ++i) {
        int flat = i * 1024 + tid * 4;
        int rr = flat >> 6, cc = flat & 63;
        float4 v = *(const float4*)(src + (size_t)(r0 + rr) * sstride + c0 + cc);
        ushort4 h4;
        h4.x = f2bf(v.x); h4.y = f2bf(v.y); h4.z = f2bf(v.z); h4.w = f2bf(v.w);
        *(ushort4*)&tile[rr][cc] = h4;
    }
    __syncthreads();
#pragma unroll
    for (int i = 0; i < 4; ++i) {
        int flat = i * 1024 + tid * 4;
        int rr = flat >> 6, cc = flat & 63;   // rr: dst row (src col), cc: dst col base (src rows)
        ushort4 o;
        o.x = tile[cc + 0][rr]; o.y = tile[cc + 1][rr];
        o.z = tile[cc + 2][rr]; o.w = tile[cc + 3][rr];
        *(ushort4*)(dst + (size_t)(c0 + rr) * dstride + r0 + cc) = o;
    }
}

// ====================== 256x256 BK=64 2-phase MFMA GEMM cores ======================
// 512 threads = 8 waves (2 M x 4 N); per-wave out 128x64; M_rep=8, N_rep=4.
// LDS 128 KiB: buf{0,1} x (A 32KB | B 32KB). Tiles are [256 rows][64 bf16 = 128B].
// Swizzle: byte_in_row ^= ((row&7)<<4)  (involution; 2-way bank alias on reads = free).
// Staging: global_load_lds 16B/lane, linear LDS dest; SOURCE address pre-applies the
// inverse swizzle (same XOR), so swizzled ds_read_b128 sees the right bytes (rule #21).

// per-lane stage geometry: each of 4 instrs covers 64 rows; lane handles
// row = i*64 + (tid>>3), swizzled byte col = ((tid&7)<<4) ^ (((tid>>3)&7)<<4)
__device__ __forceinline__ void stage8(const char* const gA[4], const char* const gB[4],
                                       char* sm_buf, int koff, int tid) {
    int lofs = __builtin_amdgcn_readfirstlane((tid >> 6) << 10);
    char* l = sm_buf + lofs;
#pragma unroll
    for (int i = 0; i < 4; ++i) {
        gload16(gA[i] + koff, l + i * 8192);
        gload16(gB[i] + koff, l + 32768 + i * 8192);
    }
}

// ---------------- GEMM1: hbuf[slot][hh] = relu(xg[slot] @ w1t[e] + b1[e]), bf16 out ----------------
__global__ __launch_bounds__(512) void gemm1_kernel(
    const u16* __restrict__ xg, const u16* __restrict__ w1t,
    const float* __restrict__ b1, u16* __restrict__ hbuf,
    const int* __restrict__ counts, const int* __restrict__ base,
    int chunk, int HC)
{
    const int e = blockIdx.z;
    const int n_e = counts[e];
    const int row0 = blockIdx.y << 8;
    if (row0 >= n_e) return;
    const int sbase = base[e];
    const int col0 = blockIdx.x << 8;
    const int tid = threadIdx.x;
    const int lane = tid & 63;
    const int wv = tid >> 6;

    __shared__ u16 sm[65536];   // 128 KiB

    // ---- stage source addresses (per lane), inverse-swizzled ----
    const int srow = tid >> 3;                                   // 0..63
    const int scol = ((tid & 7) << 4) ^ ((srow & 7) << 4);       // [0,128) bytes
    const char* gA[4]; const char* gB[4];
#pragma unroll
    for (int i = 0; i < 4; ++i) {
        int slot = sbase + row0 + i * 64 + srow;
        slot = slot < 16383 ? slot : 16383;                      // clamp expert tail (guarded at C-write)
        gA[i] = (const char*)xg + ((size_t)slot << 11) + scol;   // xg row = 1024 bf16 = 2048 B
        int hrow = col0 + i * 64 + srow;                         // < HC
        gB[i] = (const char*)w1t + (((size_t)e * HC + hrow) << 11) + scol;
    }

    // ---- fragment read offsets (swizzled) ----
    const int mrow = ((wv >> 2) << 7) + (lane & 15);
    const int nrow = ((wv & 3) << 6) + (lane & 15);
    const int ko = (lane >> 4) << 4;
    const int aoff0 = mrow * 128 + (ko ^ ((mrow & 7) << 4));
    const int aoff1 = mrow * 128 + ((64 + ko) ^ ((mrow & 7) << 4));
    const int boff0 = nrow * 128 + (ko ^ ((nrow & 7) << 4));
    const int boff1 = nrow * 128 + ((64 + ko) ^ ((nrow & 7) << 4));

    f32x4 acc[8][4];
#pragma unroll
    for (int m = 0; m < 8; ++m)
#pragma unroll
        for (int n = 0; n < 4; ++n) acc[m][n] = f32x4{0.f, 0.f, 0.f, 0.f};

    stage8(gA, gB, (char*)sm, 0, tid);
    __syncthreads();

    const int NT = D_IN / 64;   // 16
    int cur = 0;
    for (int t = 0; t < NT; ++t) {
        if (t + 1 < NT) stage8(gA, gB, (char*)sm + (cur ^ 1) * 65536, (t + 1) * 128, tid);
        const char* A = (const char*)sm + cur * 65536;
        const char* B = A + 32768;
        s16x8 a[8], b[4];
#pragma unroll
        for (int m = 0; m < 8; ++m) a[m] = *(const s16x8*)(A + aoff0 + m * 2048);
#pragma unroll
        for (int n = 0; n < 4; ++n) b[n] = *(const s16x8*)(B + boff0 + n * 2048);
#pragma unroll
        for (int m = 0; m < 8; ++m)
#pragma unroll
            for (int n = 0; n < 4; ++n) acc[m][n] = mfma16(a[m], b[n], acc[m][n]);
#pragma unroll
        for (int m = 0; m < 8; ++m) a[m] = *(const s16x8*)(A + aoff1 + m * 2048);
#pragma unroll
        for (int n = 0; n < 4; ++n) b[n] = *(const s16x8*)(B + boff1 + n * 2048);
#pragma unroll
        for (int m = 0; m < 8; ++m)
#pragma unroll
            for (int n = 0; n < 4; ++n) acc[m][n] = mfma16(a[m], b[n], acc[m][n]);
        __syncthreads();
        cur ^= 1;
    }

    // ---- epilogue: bias + relu + cvt, guarded rows ----
    const int crow = ((wv >> 2) << 7) + ((lane >> 4) << 2);
    const int ccol = ((wv & 3) << 6) + (lane & 15);
    float bias_n[4];
#pragma unroll
    for (int n = 0; n < 4; ++n)
        bias_n[n] = b1[(e << 12) + chunk * HC + col0 + ccol + n * 16];
#pragma unroll
    for (int m = 0; m < 8; ++m) {
#pragma unroll
        for (int j = 0; j < 4; ++j) {
            int rl = crow + m * 16 + j;
            int r = row0 + rl;
            if (r < n_e) {
                u16* dst = hbuf + (size_t)(sbase + r) * HC + col0;
#pragma unroll
                for (int n = 0; n < 4; ++n) {
                    float v = acc[m][n][j] + bias_n[n];
                    v = v > 0.f ? v : 0.f;
                    dst[ccol + n * 16] = f2bf(v);
                }
            }
        }
    }
}

// ---------------- GEMM2: eo[slot][o] (+)= hbuf[slot] @ w2t[e] (+ b2 on chunk 0), f32 out ----------------
__global__ __launch_bounds__(512) void gemm2_kernel(
    const u16* __restrict__ hbuf, const u16* __restrict__ w2t,
    const float* __restrict__ b2, float* __restrict__ eo,
    const int* __restrict__ counts, const int* __restrict__ base,
    int chunk, int HC)
{
    const int e = blockIdx.z;
    const int n_e = counts[e];
    const int row0 = blockIdx.y << 8;
    if (row0 >= n_e) return;
    const int sbase = base[e];
    const int col0 = blockIdx.x << 8;
    const int tid = threadIdx.x;
    const int lane = tid & 63;
    const int wv = tid >> 6;

    __shared__ u16 sm[65536];

    const int srow = tid >> 3;
    const int scol = ((tid & 7) << 4) ^ ((srow & 7) << 4);
    const char* gA[4]; const char* gB[4];
#pragma unroll
    for (int i = 0; i < 4; ++i) {
        int slot = sbase + row0 + i * 64 + srow;
        slot = slot < 16383 ? slot : 16383;
        gA[i] = (const char*)hbuf + (((size_t)slot * HC) << 1) + scol;   // hbuf row = HC bf16
        int orow = col0 + i * 64 + srow;                                  // < 1024
        gB[i] = (const char*)w2t + ((((size_t)(e << 10) + orow) * HC) << 1) + scol;
    }

    const int mrow = ((wv >> 2) << 7) + (lane & 15);
    const int nrow = ((wv & 3) << 6) + (lane & 15);
    const int ko = (lane >> 4) << 4;
    const int aoff0 = mrow * 128 + (ko ^ ((mrow & 7) << 4));
    const int aoff1 = mrow * 128 + ((64 + ko) ^ ((mrow & 7) << 4));
    const int boff0 = nrow * 128 + (ko ^ ((nrow & 7) << 4));
    const int boff1 = nrow * 128 + ((64 + ko) ^ ((nrow & 7) << 4));

    f32x4 acc[8][4];
#pragma unroll
    for (int m = 0; m < 8; ++m)
#pragma unroll
        for (int n = 0; n < 4; ++n) acc[m][n] = f32x4{0.f, 0.f, 0.f, 0.f};

    stage8(gA, gB, (char*)sm, 0, tid);
    __syncthreads();

    const int NT = HC / 64;
    int cur = 0;
    for (int t = 0; t < NT; ++t) {
        if (t + 1 < NT) stage8(gA, gB, (char*)sm + (cur ^ 1) * 65536, (t + 1) * 128, tid);
        const char* A = (const char*)sm + cur * 65536;
        const char* B = A + 32768;
        s16x8 a[8], b[4];
#pragma unroll
        for (int m = 0; m < 8; ++m) a[m] = *(const s16x8*)(A + aoff0 + m * 2048);
#pragma unroll
        for (int n = 0; n < 4; ++n) b[n] = *(const s16x8*)(B + boff0 + n * 2048);
#pragma unroll
        for (int m = 0; m < 8; ++m)
#pragma unroll
            for (int n = 0; n < 4; ++n) acc[m][n] = mfma16(a[m], b[n], acc[m][n]);
#pragma unroll
        for (int m = 0; m < 8; ++m) a[m] = *(const s16x8*)(A + aoff1 + m * 2048);
#pragma unroll
        for (int n = 0; n < 4; ++n) b[n] = *(const s16x8*)(B + boff1 + n * 2048);
#pragma unroll
        for (int m = 0; m < 8; ++m)
#pragma unroll
            for (int n = 0; n < 4; ++n) acc[m][n] = mfma16(a[m], b[n], acc[m][n]);
        __syncthreads();
        cur ^= 1;
    }

    const int crow = ((wv >> 2) << 7) + ((lane >> 4) << 2);
    const int ccol = ((wv & 3) << 6) + (lane & 15);
    float bias_n[4];
#pragma unroll
    for (int n = 0; n < 4; ++n)
        bias_n[n] = (chunk == 0) ? b2[(e << 10) + col0 + ccol + n * 16] : 0.f;
#pragma unroll
    for (int m = 0; m < 8; ++m) {
#pragma unroll
        for (int j = 0; j < 4; ++j) {
            int rl = crow + m * 16 + j;
            int r = row0 + rl;
            if (r < n_e) {
                float* dst = eo + ((size_t)(sbase + r) << 10) + col0;
#pragma unroll
                for (int n = 0; n < 4; ++n) {
                    int c = ccol + n * 16;
                    float v = acc[m][n][j] + bias_n[n];
                    if (chunk) v += dst[c];
                    dst[c] = v;
                }
            }
        }
    }
}

// ---------------- combine: out[t] = w0*eo[s0] + w1*eo[s1] (deterministic) ----------------
__global__ __launch_bounds__(256) void combine_kernel(
    const float* __restrict__ eo, const float* __restrict__ weights,
    const int* __restrict__ slot_of_tok, const int* __restrict__ base,
    float* __restrict__ out)
{
    const int t = blockIdx.x;
    const int tid = threadIdx.x;
    int s0 = slot_of_tok[t * 2], s1 = slot_of_tok[t * 2 + 1];
    int e0 = s0 >> 13, e1 = s1 >> 13;
    int c0 = base[e0] + (s0 & 8191);
    int c1 = base[e1] + (s1 & 8191);
    float w0 = weights[t * 8 + e0];
    float w1 = weights[t * 8 + e1];
    int c = tid * 4;
    f32x4 a = *(const f32x4*)(eo + ((size_t)c0 << 10) + c);
    f32x4 b = *(const f32x4*)(eo + ((size_t)c1 << 10) + c);
    f32x4 r;
    r[0] = w0 * a[0] + w1 * b[0];
    r[1] = w0 * a[1] + w1 * b[1];
    r[2] = w0 * a[2] + w1 * b[2];
    r[3] = w0 * a[3] + w1 * b[3];
    *(f32x4*)(out + ((size_t)t << 10) + c) = r;
}

extern "C" void kernel_launch(void* const* d_in, const int* in_sizes, int n_in,
                              void* d_out, int out_size, void* d_ws, size_t ws_size,
                              hipStream_t stream)
{
    const float* x      = (const float*)d_in[0];
    const float* gate_w = (const float*)d_in[1];
    const float* gate_b = (const float*)d_in[2];
    const float* w1     = (const float*)d_in[3];
    const float* b1     = (const float*)d_in[4];
    const float* w2     = (const float*)d_in[5];
    const float* b2     = (const float*)d_in[6];

    float* out         = (float*)d_out;                      // [8192,1024]
    float* weights_out = out + (size_t)T_TOK * DO_DIM;       // [8192,8]
    float* usage_out   = weights_out + (size_t)T_TOK * 8;    // [8]
    float* topi_out    = usage_out + 8;                      // [8192,2]

    char* p = (char*)d_ws;
    int* counts = (int*)p;       p += 256;
    int* base   = (int*)p;       p += 256;
    int* tok_list = (int*)p;     p += (size_t)8 * 8192 * 4;
    int* slot_of_tok = (int*)p;  p += (size_t)8192 * 2 * 4;
    const size_t fixed = (size_t)(p - (char*)d_ws);

    // xg 32MiB + eo 64MiB fixed; per-HC: w1t 16*HC KiB... total var = 65536*HC
    const size_t xg_bytes = (size_t)16384 * 1024 * 2;
    const size_t eo_bytes = (size_t)16384 * 1024 * 4;
    int HC;
    if      (ws_size >= fixed + xg_bytes + eo_bytes + (size_t)65536 * 4096) HC = 4096;
    else if (ws_size >= fixed + xg_bytes + eo_bytes + (size_t)65536 * 2048) HC = 2048;
    else if (ws_size >= fixed + xg_bytes + eo_bytes + (size_t)65536 * 1024) HC = 1024;
    else                                                                    HC = 512;

    u16* xg   = (u16*)p; p += xg_bytes;
    u16* w1t  = (u16*)p; p += (size_t)8 * HC * 1024 * 2;
    u16* w2t  = (u16*)p; p += (size_t)8 * 1024 * HC * 2;
    u16* hbuf = (u16*)p; p += (size_t)16384 * HC * 2;
    float* eo = (float*)p;

    zero_counts_kernel<<<1, 64, 0, stream>>>(counts);
    gate_kernel<<<T_TOK, 256, 0, stream>>>(x, gate_w, gate_b, weights_out, topi_out,
                                           counts, tok_list, slot_of_tok);
    scan_kernel<<<1, 64, 0, stream>>>(counts, base, usage_out);
    gather_kernel<<<dim3(T_TOK, 8), 256, 0, stream>>>(x, counts, base, tok_list, xg);

    const int NC = H_DIM / HC;
    for (int c = 0; c < NC; ++c) {
        int tiles_h = HC / 64;
        transpose_kernel<<<dim3(2 * 16 * tiles_h, 1, 8), 256, 0, stream>>>(w1, w2, w1t, w2t, c, HC);
        gemm1_kernel<<<dim3(HC / 256, 32, 8), 512, 0, stream>>>(xg, w1t, b1, hbuf,
                                                                counts, base, c, HC);
        gemm2_kernel<<<dim3(DO_DIM / 256, 32, 8), 512, 0, stream>>>(hbuf, w2t, b2, eo,
                                                                    counts, base, c, HC);
    }
    combine_kernel<<<T_TOK, 256, 0, stream>>>(eo, weights_out, slot_of_tok, base, out);
}